// Round 9
// baseline (210.379 us; speedup 1.0000x reference)
//
#include <hip/hip_runtime.h>
#include <hip/hip_bf16.h>
#include <hip/hip_fp16.h>

#define NT 4096
#define NE 131072

// ws layout (bytes)
#define OFF_DEG  0            // float[4096]
#define OFF_A    16384        // bf16[4096*4096] = 32 MiB
#define OFF_G1T  33570816     // bf16[16][4096]
#define OFF_G2T  33701888     // bf16[32][4096]
#define OFF_G3T  33964032     // bf16[32][4096]
#define OFF_H3   34226176     // bf16[4096][32]
#define OFF_W2T  34488320     // uint[1568]
// total ~34.5 MB

typedef __attribute__((ext_vector_type(8))) short bf16x8;
typedef __attribute__((ext_vector_type(4))) float f32x4;

__device__ inline unsigned int align16(unsigned int hi, unsigned int lo) {
#if __has_builtin(__builtin_amdgcn_alignbit)
    return __builtin_amdgcn_alignbit(hi, lo, 16);
#else
    return (lo >> 16) | (hi << 16);
#endif
}

__device__ inline unsigned short bfb(float x) {
    return __hip_bfloat16_raw(__float2bfloat16(x)).x;
}

__device__ inline void atomic_add_bf16(unsigned short* base, unsigned int idx, float v) {
    unsigned long long addr = (unsigned long long)(base + (idx & ~1u));
    unsigned int bits = ((unsigned int)bfb(v)) << ((idx & 1u) * 16);
    asm volatile("global_atomic_pk_add_bf16 %0, %1, off" :: "v"(addr), "v"(bits) : "memory");
}

// ---------------- setup ----------------

// zero dense A (streaming) + degree atomics; deg pre-zeroed by tiny memset
__global__ __launch_bounds__(256) void k_zerodeg(const int* __restrict__ ei,
                                                 const float* __restrict__ ew,
                                                 float* __restrict__ deg,
                                                 unsigned short* __restrict__ A16) {
    int blk = blockIdx.x, tid = threadIdx.x;
    uint4 z4 = {0u, 0u, 0u, 0u};
    uint4* ap = (uint4*)(A16 + (size_t)blk * 16384);
    #pragma unroll
    for (int k = 0; k < 8; k++) ap[tid + k * 256] = z4;
    int gid = blk * 256 + tid;
    if (gid < NE) atomicAdd(&deg[ei[NE + gid]], ew[gid]);
}

__global__ void k_scatter(const int* __restrict__ ei, const float* __restrict__ ew,
                          const float* __restrict__ deg, unsigned short* __restrict__ A16,
                          const float* __restrict__ x, const float* __restrict__ W0,
                          unsigned short* __restrict__ G1T,
                          const float* __restrict__ Wp, unsigned int* __restrict__ w2) {
    int e = blockIdx.x * 256 + threadIdx.x;
    if (e < NE) {
        int s = ei[e], d = ei[NE + e];
        float v = rsqrtf(deg[s] + 2.f) * ew[e] * rsqrtf(deg[d] + 2.f);
        atomic_add_bf16(A16, (unsigned int)d * 4096u + (unsigned int)s, v);
    }
    if (e < NT) {
        atomic_add_bf16(A16, (unsigned int)e * 4097u, 2.f / (deg[e] + 2.f));
    }
    if (e < NT * 16) {
        int node = e & 4095, co = e >> 12;
        const float4* xr = (const float4*)(x + node * 32);
        float a = 0.f;
        #pragma unroll
        for (int r = 0; r < 8; r++) {
            float4 f = xr[r];
            a += f.x * W0[(r*4+0)*16 + co] + f.y * W0[(r*4+1)*16 + co]
               + f.z * W0[(r*4+2)*16 + co] + f.w * W0[(r*4+3)*16 + co];
        }
        G1T[co * 4096 + node] = bfb(a);
    }
    if (e >= NE - 1568) {
        int k = e - (NE - 1568);
        __half hh = __float2half(Wp[k]);
        __half2 h2 = __halves2half2(hh, hh);
        w2[k] = *(unsigned int*)&h2;
    }
}

// ---------------- GCN layer via dense-A MFMA, A register-prefetched ----------------

template <int NIN, int NOUT, bool LAST>
__global__ __launch_bounds__(512) void k_gcn(const unsigned short* __restrict__ A16,
                                             const unsigned short* __restrict__ Gt,
                                             const float* __restrict__ bias,
                                             const float* __restrict__ W,
                                             unsigned short* __restrict__ Gout) {
    constexpr int T = NIN / 16;
    __shared__ float red[8][T][16][16];
    __shared__ unsigned short wtile[16 * 40];
    int mt = blockIdx.x;
    int tid = threadIdx.x;
    int w = tid >> 6, lane = tid & 63, m = lane & 15, q = lane >> 4;
    int kw = w * 512;

    const unsigned short* arow = A16 + (size_t)(mt * 16 + m) * 4096 + kw + q * 8;

    // prefetch the whole A stream for this wave's K-window (16 x b128 in flight)
    bf16x8 bA[16];
    #pragma unroll
    for (int s = 0; s < 16; s++) bA[s] = *(const bf16x8*)(arow + s * 32);

    f32x4 acc[T];
    #pragma unroll
    for (int t = 0; t < T; t++) acc[t] = (f32x4){0.f, 0.f, 0.f, 0.f};

    bf16x8 wfrag;
    if (!LAST && w < NOUT / 16) {
        #pragma unroll
        for (int j = 0; j < 8; j++) {
            int ci = q * 8 + j;
            wfrag[j] = (ci < NIN) ? (short)bfb(W[ci * NOUT + w * 16 + m]) : (short)0;
        }
    }

    const unsigned short* gbase = Gt + kw + q * 8 + (size_t)m * 4096;
    #pragma unroll
    for (int s = 0; s < 16; s++) {
        #pragma unroll
        for (int t = 0; t < T; t++) {
            bf16x8 af = *(const bf16x8*)(gbase + (size_t)t * 16 * 4096 + s * 32);
            acc[t] = __builtin_amdgcn_mfma_f32_16x16x32_bf16(af, bA[s], acc[t], 0, 0, 0);
        }
    }
    #pragma unroll
    for (int t = 0; t < T; t++)
        #pragma unroll
        for (int r = 0; r < 4; r++) red[w][t][q*4 + r][m] = acc[t][r];
    __syncthreads();

    if (tid < T * 256) {
        int dstp = tid & 15, cop = (tid >> 4) & 15, t = tid >> 8;
        float sum = 0.f;
        #pragma unroll
        for (int w8 = 0; w8 < 8; w8++) sum += red[w8][t][cop][dstp];
        int co = t * 16 + cop;
        float val = fmaxf(sum + bias[co], 0.f);
        if (LAST) Gout[(size_t)(mt * 16 + dstp) * 32 + co] = bfb(val);
        else      wtile[dstp * 40 + co] = bfb(val);
    }
    if (!LAST && NIN == 16 && tid >= 256 && tid < 512) {
        int idx = tid - 256;
        wtile[(idx & 15) * 40 + 16 + ((idx >> 4) & 15)] = 0;
    }
    __syncthreads();

    if (!LAST && w < NOUT / 16) {
        bf16x8 af = *(const bf16x8*)&wtile[m * 40 + q * 8];
        f32x4 o = (f32x4){0.f, 0.f, 0.f, 0.f};
        o = __builtin_amdgcn_mfma_f32_16x16x32_bf16(af, wfrag, o, 0, 0, 0);
        uint2 ov;
        ov.x = (unsigned int)bfb(o[0]) | ((unsigned int)bfb(o[1]) << 16);
        ov.y = (unsigned int)bfb(o[2]) | ((unsigned int)bfb(o[3]) << 16);
        *(uint2*)&Gout[(size_t)(w * 16 + m) * 4096 + mt * 16 + q * 4] = ov;
    }
}

// ---------------- fused C1 + 7x7 conv + sigmoid (v3) ----------------
// grid (band 16, b 16) = 256 blocks, 512 thr. Band = 16 out rows, j full 256.
// 16 iters x 2 channels: MFMA phase writes 2 LDS planes (32 rows x stride 280
// f16, col j+4, halos zero); conv phase: each thread 1 out-row x 8 px x BOTH
// channels (no group split, no reduction). zs overlapped by ct (dead after
// frag extraction). LDS ~40 KB.

__global__ __launch_bounds__(512) void k_cc(const unsigned short* __restrict__ h3,
                                            const float* __restrict__ Wc,
                                            const float* __restrict__ bc,
                                            const unsigned int* __restrict__ w2,
                                            const float* __restrict__ bp,
                                            float* __restrict__ out) {
    __shared__ __align__(16) unsigned short pool[2 * 32 * 280];  // 35840 B (zs = first 20480 B)
    __shared__ float wcs[32 * 36];                               // 4608 B

    int band = blockIdx.x, bb = blockIdx.y;
    int i0 = band * 16;
    int tid = threadIdx.x;
    int lane = tid & 63, w = tid >> 6;
    int m = lane & 15, q = lane >> 4;

    unsigned short* zs = pool;

    // ---- stage Z_b into zs (row stride 40 f16) ----
    {
        int row = tid >> 1, half = tid & 1;
        const uint4* src = (const uint4*)(h3 + (size_t)(bb * 256 + row) * 32) + half * 2;
        uint4 v0 = src[0], v1 = src[1];
        uint4* dst = (uint4*)&zs[row * 40 + half * 16];
        dst[0] = v0; dst[1] = v1;
    }
    #pragma unroll
    for (int k = tid; k < 1024; k += 512) wcs[(k >> 5) * 36 + (k & 31)] = Wc[k];
    __syncthreads();

    // ---- extract frags to registers ----
    bf16x8 bt[2];          // B operand: i-rows i0-3+nt*16+m
    bool wok[2];
    #pragma unroll
    for (int nt = 0; nt < 2; nt++) {
        int r = i0 - 3 + nt * 16 + m;
        wok[nt] = (unsigned)r < 256u;
        r = r < 0 ? 0 : (r > 255 ? 255 : r);
        bt[nt] = *(const bf16x8*)&zs[r * 40 + q * 8];
    }
    float zaf[2][8];       // A base: j-rows (w*2+jt2)*16+m
    #pragma unroll
    for (int jt2 = 0; jt2 < 2; jt2++) {
        bf16x8 za = *(const bf16x8*)&zs[((w * 2 + jt2) * 16 + m) * 40 + q * 8];
        #pragma unroll
        for (int e = 0; e < 8; e++)
            zaf[jt2][e] = __uint_as_float(((unsigned int)(unsigned short)za[e]) << 16);
    }
    __syncthreads();       // zs dead; pool becomes ct

    // ---- zero ct (2 planes x 32 rows x 280 f16 = 8960 dw) ----
    for (int k = tid; k < 8960; k += 512) ((unsigned int*)pool)[k] = 0;

    int tx = tid & 31, ty = tid >> 5;   // 8 px, 1 out row (ty 0..15)
    __half2 acc[4];
    __half2 zh = __float2half2_rn(0.f);
    #pragma unroll
    for (int p = 0; p < 4; p++) acc[p] = zh;
    __syncthreads();

    for (int it = 0; it < 16; it++) {
        // ---- MFMA phase: channels it*2, it*2+1 ----
        #pragma unroll
        for (int g = 0; g < 2; g++) {
            int h = it * 2 + g;
            float wf[8];
            *(float4*)&wf[0] = *(const float4*)&wcs[h * 36 + q * 8];
            *(float4*)&wf[4] = *(const float4*)&wcs[h * 36 + q * 8 + 4];
            float bch = bc[h];
            #pragma unroll
            for (int jt2 = 0; jt2 < 2; jt2++) {
                bf16x8 afv;
                #pragma unroll
                for (int e = 0; e < 8; e++) afv[e] = (short)bfb(zaf[jt2][e] * wf[e]);
                int pos = 4 + (w * 2 + jt2) * 16 + q * 4;
                #pragma unroll
                for (int nt = 0; nt < 2; nt++) {
                    f32x4 d = (f32x4){0.f, 0.f, 0.f, 0.f};
                    d = __builtin_amdgcn_mfma_f32_16x16x32_bf16(afv, bt[nt], d, 0, 0, 0);
                    if (wok[nt]) {
                        float v0 = fmaxf(d[0] + bch, 0.f);
                        float v1 = fmaxf(d[1] + bch, 0.f);
                        float v2 = fmaxf(d[2] + bch, 0.f);
                        float v3 = fmaxf(d[3] + bch, 0.f);
                        __half2 h0 = __floats2half2_rn(v0, v1);
                        __half2 h1 = __floats2half2_rn(v2, v3);
                        uint2 o2;
                        o2.x = *(unsigned int*)&h0;
                        o2.y = *(unsigned int*)&h1;
                        *(uint2*)&pool[g * 8960 + (nt * 16 + m) * 280 + pos] = o2;
                    }
                }
            }
        }
        __syncthreads();

        // ---- conv phase: this thread's row/pixels, both channels ----
        #pragma unroll
        for (int g = 0; g < 2; g++) {
            const unsigned short* C = pool + g * 8960;
            const __half2* wrow = (const __half2*)w2 + (it * 2 + g) * 49;
            uint4 ra[7], rb[7];
            #pragma unroll
            for (int dr = 0; dr < 7; dr++) {
                const uint4* p4 = (const uint4*)&C[(ty + dr) * 280 + tx * 8];
                ra[dr] = p4[0];
                rb[dr] = p4[1];
            }
            #pragma unroll
            for (int dr = 0; dr < 7; dr++) {
                unsigned int E[8] = {ra[dr].x, ra[dr].y, ra[dr].z, ra[dr].w,
                                     rb[dr].x, rb[dr].y, rb[dr].z, rb[dr].w};
                unsigned int O[7];
                #pragma unroll
                for (int k = 0; k < 7; k++) O[k] = align16(E[k + 1], E[k]);
                #pragma unroll
                for (int dj = 0; dj < 7; dj++) {
                    __half2 wv = wrow[dr * 7 + dj];
                    #pragma unroll
                    for (int pr = 0; pr < 4; pr++) {
                        int s = 2 * pr + dj + 1;
                        unsigned int pv = (s & 1) ? O[s >> 1] : E[s >> 1];
                        acc[pr] = __hfma2(wv, *(__half2*)&pv, acc[pr]);
                    }
                }
            }
        }
        __syncthreads();
    }

    // ---- sigmoid + store (no cross-thread reduce needed) ----
    {
        float bpv = bp[0];
        float fs[8];
        #pragma unroll
        for (int pr = 0; pr < 4; pr++) {
            float2 f = __half22float2(acc[pr]);
            fs[2 * pr] = f.x; fs[2 * pr + 1] = f.y;
        }
        float rs[8];
        #pragma unroll
        for (int e = 0; e < 8; e++) rs[e] = 1.0f / (1.0f + __expf(-(fs[e] + bpv)));
        float* op = &out[((size_t)(bb * 256) + i0 + ty) * 256 + tx * 8];
        *(float4*)op = make_float4(rs[0], rs[1], rs[2], rs[3]);
        *(float4*)(op + 4) = make_float4(rs[4], rs[5], rs[6], rs[7]);
    }
}

// ---------------- launch ----------------

extern "C" void kernel_launch(void* const* d_in, const int* in_sizes, int n_in,
                              void* d_out, int out_size, void* d_ws, size_t ws_size,
                              hipStream_t stream) {
    const float* x  = (const float*)d_in[0];
    const int*   ei = (const int*)d_in[1];
    const float* ew = (const float*)d_in[2];
    const float* W0 = (const float*)d_in[4];
    const float* b0 = (const float*)d_in[5];
    const float* W1 = (const float*)d_in[6];
    const float* b1 = (const float*)d_in[7];
    const float* W2 = (const float*)d_in[8];
    const float* b2 = (const float*)d_in[9];
    const float* Wc = (const float*)d_in[10];
    const float* bc = (const float*)d_in[11];
    const float* Wp = (const float*)d_in[12];
    const float* bp = (const float*)d_in[13];

    char* ws = (char*)d_ws;
    float*          deg  = (float*)(ws + OFF_DEG);
    unsigned short* A16  = (unsigned short*)(ws + OFF_A);
    unsigned short* G1T  = (unsigned short*)(ws + OFF_G1T);
    unsigned short* G2T  = (unsigned short*)(ws + OFF_G2T);
    unsigned short* G3T  = (unsigned short*)(ws + OFF_G3T);
    unsigned short* H3   = (unsigned short*)(ws + OFF_H3);
    unsigned int*   w2t  = (unsigned int*)(ws + OFF_W2T);

    (void)hipMemsetAsync(deg, 0, 16384, stream);   // deg only (A zeroed in-kernel)

    k_zerodeg<<<1024, 256, 0, stream>>>(ei, ew, deg, A16);
    k_scatter<<<NE/256, 256, 0, stream>>>(ei, ew, deg, A16, x, W0, G1T, Wp, w2t);

    k_gcn<16, 32, false><<<256, 512, 0, stream>>>(A16, G1T, b0, W1, G2T);
    k_gcn<32, 32, false><<<256, 512, 0, stream>>>(A16, G2T, b1, W2, G3T);
    k_gcn<32, 32, true> <<<256, 512, 0, stream>>>(A16, G3T, b2, nullptr, H3);

    k_cc<<<dim3(16, 16), 512, 0, stream>>>(H3, Wc, bc, w2t, bp, (float*)d_out);
}

// Round 10
// 196.290 us; speedup vs baseline: 1.0718x; 1.0718x over previous
//
#include <hip/hip_runtime.h>
#include <hip/hip_bf16.h>
#include <hip/hip_fp16.h>

#define NT 4096
#define NE 131072

// ws layout (bytes)
#define OFF_DEG  0            // float[4096]
#define OFF_A    16384        // bf16[4096*4096] = 32 MiB
#define OFF_G1T  33570816     // bf16[16][4096]
#define OFF_G2T  33701888     // bf16[32][4096]
#define OFF_G3T  33964032     // bf16[32][4096]
#define OFF_H3   34226176     // bf16[4096][32]
#define OFF_W2T  34488320     // uint[1568]
// total ~34.5 MB

typedef __attribute__((ext_vector_type(8))) short bf16x8;
typedef __attribute__((ext_vector_type(4))) float f32x4;

__device__ inline unsigned int align16(unsigned int hi, unsigned int lo) {
#if __has_builtin(__builtin_amdgcn_alignbit)
    return __builtin_amdgcn_alignbit(hi, lo, 16);
#else
    return (lo >> 16) | (hi << 16);
#endif
}

__device__ inline unsigned short bfb(float x) {
    return __hip_bfloat16_raw(__float2bfloat16(x)).x;
}

__device__ inline void atomic_add_bf16(unsigned short* base, unsigned int idx, float v) {
    unsigned long long addr = (unsigned long long)(base + (idx & ~1u));
    unsigned int bits = ((unsigned int)bfb(v)) << ((idx & 1u) * 16);
    asm volatile("global_atomic_pk_add_bf16 %0, %1, off" :: "v"(addr), "v"(bits) : "memory");
}

// ---------------- setup ----------------

__global__ __launch_bounds__(256) void k_zerodeg(const int* __restrict__ ei,
                                                 const float* __restrict__ ew,
                                                 float* __restrict__ deg,
                                                 unsigned short* __restrict__ A16) {
    int blk = blockIdx.x, tid = threadIdx.x;
    uint4 z4 = {0u, 0u, 0u, 0u};
    uint4* ap = (uint4*)(A16 + (size_t)blk * 16384);
    #pragma unroll
    for (int k = 0; k < 8; k++) ap[tid + k * 256] = z4;
    int gid = blk * 256 + tid;
    if (gid < NE) atomicAdd(&deg[ei[NE + gid]], ew[gid]);
}

__global__ void k_scatter(const int* __restrict__ ei, const float* __restrict__ ew,
                          const float* __restrict__ deg, unsigned short* __restrict__ A16,
                          const float* __restrict__ x, const float* __restrict__ W0,
                          unsigned short* __restrict__ G1T,
                          const float* __restrict__ Wp, unsigned int* __restrict__ w2) {
    int e = blockIdx.x * 256 + threadIdx.x;
    if (e < NE) {
        int s = ei[e], d = ei[NE + e];
        float v = rsqrtf(deg[s] + 2.f) * ew[e] * rsqrtf(deg[d] + 2.f);
        atomic_add_bf16(A16, (unsigned int)d * 4096u + (unsigned int)s, v);
    }
    if (e < NT) {
        atomic_add_bf16(A16, (unsigned int)e * 4097u, 2.f / (deg[e] + 2.f));
    }
    if (e < NT * 16) {
        int node = e & 4095, co = e >> 12;
        const float4* xr = (const float4*)(x + node * 32);
        float a = 0.f;
        #pragma unroll
        for (int r = 0; r < 8; r++) {
            float4 f = xr[r];
            a += f.x * W0[(r*4+0)*16 + co] + f.y * W0[(r*4+1)*16 + co]
               + f.z * W0[(r*4+2)*16 + co] + f.w * W0[(r*4+3)*16 + co];
        }
        G1T[co * 4096 + node] = bfb(a);
    }
    if (e >= NE - 1568) {
        int k = e - (NE - 1568);
        __half hh = __float2half(Wp[k]);
        __half2 h2 = __halves2half2(hh, hh);
        w2[k] = *(unsigned int*)&h2;
    }
}

// ---------------- GCN layer via dense-A MFMA, A register-prefetched ----------------

template <int NIN, int NOUT, bool LAST>
__global__ __launch_bounds__(512) void k_gcn(const unsigned short* __restrict__ A16,
                                             const unsigned short* __restrict__ Gt,
                                             const float* __restrict__ bias,
                                             const float* __restrict__ W,
                                             unsigned short* __restrict__ Gout) {
    constexpr int T = NIN / 16;
    __shared__ float red[8][T][16][16];
    __shared__ unsigned short wtile[16 * 40];
    int mt = blockIdx.x;
    int tid = threadIdx.x;
    int w = tid >> 6, lane = tid & 63, m = lane & 15, q = lane >> 4;
    int kw = w * 512;

    const unsigned short* arow = A16 + (size_t)(mt * 16 + m) * 4096 + kw + q * 8;

    bf16x8 bA[16];
    #pragma unroll
    for (int s = 0; s < 16; s++) bA[s] = *(const bf16x8*)(arow + s * 32);

    f32x4 acc[T];
    #pragma unroll
    for (int t = 0; t < T; t++) acc[t] = (f32x4){0.f, 0.f, 0.f, 0.f};

    bf16x8 wfrag;
    if (!LAST && w < NOUT / 16) {
        #pragma unroll
        for (int j = 0; j < 8; j++) {
            int ci = q * 8 + j;
            wfrag[j] = (ci < NIN) ? (short)bfb(W[ci * NOUT + w * 16 + m]) : (short)0;
        }
    }

    const unsigned short* gbase = Gt + kw + q * 8 + (size_t)m * 4096;
    #pragma unroll
    for (int s = 0; s < 16; s++) {
        #pragma unroll
        for (int t = 0; t < T; t++) {
            bf16x8 af = *(const bf16x8*)(gbase + (size_t)t * 16 * 4096 + s * 32);
            acc[t] = __builtin_amdgcn_mfma_f32_16x16x32_bf16(af, bA[s], acc[t], 0, 0, 0);
        }
    }
    #pragma unroll
    for (int t = 0; t < T; t++)
        #pragma unroll
        for (int r = 0; r < 4; r++) red[w][t][q*4 + r][m] = acc[t][r];
    __syncthreads();

    if (tid < T * 256) {
        int dstp = tid & 15, cop = (tid >> 4) & 15, t = tid >> 8;
        float sum = 0.f;
        #pragma unroll
        for (int w8 = 0; w8 < 8; w8++) sum += red[w8][t][cop][dstp];
        int co = t * 16 + cop;
        float val = fmaxf(sum + bias[co], 0.f);
        if (LAST) Gout[(size_t)(mt * 16 + dstp) * 32 + co] = bfb(val);
        else      wtile[dstp * 40 + co] = bfb(val);
    }
    if (!LAST && NIN == 16 && tid >= 256 && tid < 512) {
        int idx = tid - 256;
        wtile[(idx & 15) * 40 + 16 + ((idx >> 4) & 15)] = 0;
    }
    __syncthreads();

    if (!LAST && w < NOUT / 16) {
        bf16x8 af = *(const bf16x8*)&wtile[m * 40 + q * 8];
        f32x4 o = (f32x4){0.f, 0.f, 0.f, 0.f};
        o = __builtin_amdgcn_mfma_f32_16x16x32_bf16(af, wfrag, o, 0, 0, 0);
        uint2 ov;
        ov.x = (unsigned int)bfb(o[0]) | ((unsigned int)bfb(o[1]) << 16);
        ov.y = (unsigned int)bfb(o[2]) | ((unsigned int)bfb(o[3]) << 16);
        *(uint2*)&Gout[(size_t)(w * 16 + m) * 4096 + mt * 16 + q * 4] = ov;
    }
}

// ---------------- fused C1 + 7x7 conv + sigmoid (v4) ----------------
// grid (band 32, b 16) = 512 blocks (2/CU), 512 thr. Band = 8 out rows.
// LDS pool (lifetime-overlapped): zs (20480 B) -> ct (4 planes x 14 rows x
// 280 f16 = 31360 B) -> pt (4 x 2048 f16 = 16384 B); + wcs. Total ~36 KB.
// 8 iters x 4 channels: MFMA phase (1 tile/channel, rows i0-3..i0+12) ->
// conv phase (4 groups x 128 thr; thread = 2 rows x 8 px, one channel).

__global__ __launch_bounds__(512, 4) void k_cc(const unsigned short* __restrict__ h3,
                                               const float* __restrict__ Wc,
                                               const float* __restrict__ bc,
                                               const unsigned int* __restrict__ w2,
                                               const float* __restrict__ bp,
                                               float* __restrict__ out) {
    __shared__ __align__(16) unsigned short pool[15680];   // 31360 B
    __shared__ float wcs[32 * 36];                         // 4608 B

    int band = blockIdx.x, bb = blockIdx.y;
    int i0 = band * 8;
    int tid = threadIdx.x;
    int lane = tid & 63, w = tid >> 6;
    int m = lane & 15, q = lane >> 4;

    // ---- stage Z_b into pool-as-zs (row stride 40 f16) ----
    {
        int row = tid >> 1, half = tid & 1;
        const uint4* src = (const uint4*)(h3 + (size_t)(bb * 256 + row) * 32) + half * 2;
        uint4 v0 = src[0], v1 = src[1];
        uint4* dst = (uint4*)&pool[row * 40 + half * 16];
        dst[0] = v0; dst[1] = v1;
    }
    #pragma unroll
    for (int k = tid; k < 1024; k += 512) wcs[(k >> 5) * 36 + (k & 31)] = Wc[k];
    __syncthreads();

    // ---- extract frags ----
    bf16x8 bt;          // B operand: i-rows i0-3+m (single 16-row tile)
    bool wok;
    {
        int r = i0 - 3 + m;
        wok = ((unsigned)r < 256u) && (m < 14);
        int rc = r < 0 ? 0 : (r > 255 ? 255 : r);
        bt = *(const bf16x8*)&pool[rc * 40 + q * 8];
    }
    float zaf[2][8];    // A base: j-rows (w*2+jt2)*16+m
    #pragma unroll
    for (int jt2 = 0; jt2 < 2; jt2++) {
        bf16x8 za = *(const bf16x8*)&pool[((w * 2 + jt2) * 16 + m) * 40 + q * 8];
        #pragma unroll
        for (int e = 0; e < 8; e++)
            zaf[jt2][e] = __uint_as_float(((unsigned int)(unsigned short)za[e]) << 16);
    }
    __syncthreads();    // zs dead

    // ---- zero ct (7840 dw) ----
    for (int k = tid; k < 7840; k += 512) ((unsigned int*)pool)[k] = 0;
    __syncthreads();

    int gg = tid >> 7, idx = tid & 127;
    int tx = idx & 31, ty = idx >> 5;     // 8 px, 2 out rows (ty*2, ty*2+1)
    __half2 acc[2][4];
    __half2 zh = __float2half2_rn(0.f);
    #pragma unroll
    for (int o = 0; o < 2; o++)
        #pragma unroll
        for (int p = 0; p < 4; p++) acc[o][p] = zh;

    for (int it = 0; it < 8; it++) {
        // ---- MFMA phase: channels it*4 .. it*4+3 ----
        #pragma unroll
        for (int g = 0; g < 4; g++) {
            int h = it * 4 + g;
            float wf[8];
            *(float4*)&wf[0] = *(const float4*)&wcs[h * 36 + q * 8];
            *(float4*)&wf[4] = *(const float4*)&wcs[h * 36 + q * 8 + 4];
            float bch = bc[h];
            #pragma unroll
            for (int jt2 = 0; jt2 < 2; jt2++) {
                bf16x8 afv;
                #pragma unroll
                for (int e = 0; e < 8; e++) afv[e] = (short)bfb(zaf[jt2][e] * wf[e]);
                int pos = 4 + (w * 2 + jt2) * 16 + q * 4;
                f32x4 d = (f32x4){0.f, 0.f, 0.f, 0.f};
                d = __builtin_amdgcn_mfma_f32_16x16x32_bf16(afv, bt, d, 0, 0, 0);
                if (wok) {
                    float v0 = fmaxf(d[0] + bch, 0.f);
                    float v1 = fmaxf(d[1] + bch, 0.f);
                    float v2 = fmaxf(d[2] + bch, 0.f);
                    float v3 = fmaxf(d[3] + bch, 0.f);
                    __half2 h0 = __floats2half2_rn(v0, v1);
                    __half2 h1 = __floats2half2_rn(v2, v3);
                    uint2 o2;
                    o2.x = *(unsigned int*)&h0;
                    o2.y = *(unsigned int*)&h1;
                    *(uint2*)&pool[g * 3920 + m * 280 + pos] = o2;
                }
            }
        }
        __syncthreads();

        // ---- conv phase: group gg, channel it*4+gg ----
        {
            const unsigned short* C = pool + gg * 3920;
            const __half2* wrow = (const __half2*)w2 + (it * 4 + gg) * 49;
            #pragma unroll
            for (int dr = 0; dr < 8; dr++) {
                const uint4* p4 = (const uint4*)&C[(ty * 2 + dr) * 280 + tx * 8];
                uint4 ua = p4[0], ub = p4[1];
                unsigned int E[8] = {ua.x, ua.y, ua.z, ua.w, ub.x, ub.y, ub.z, ub.w};
                unsigned int O[7];
                #pragma unroll
                for (int k = 0; k < 7; k++) O[k] = align16(E[k + 1], E[k]);
                #pragma unroll
                for (int o = 0; o < 2; o++) {
                    if (dr - o < 0 || dr - o > 6) continue;   // compile-time
                    int di = dr - o;
                    #pragma unroll
                    for (int dj = 0; dj < 7; dj++) {
                        __half2 wv = wrow[di * 7 + dj];
                        #pragma unroll
                        for (int pr = 0; pr < 4; pr++) {
                            int s = 2 * pr + dj + 1;
                            unsigned int pv = (s & 1) ? O[s >> 1] : E[s >> 1];
                            acc[o][pr] = __hfma2(wv, *(__half2*)&pv, acc[o][pr]);
                        }
                    }
                }
            }
        }
        __syncthreads();
    }

    // ---- pt partials (pool reused), reduce, sigmoid, store ----
    #pragma unroll
    for (int o = 0; o < 2; o++) {
        uint4 v;
        v.x = *(unsigned int*)&acc[o][0];
        v.y = *(unsigned int*)&acc[o][1];
        v.z = *(unsigned int*)&acc[o][2];
        v.w = *(unsigned int*)&acc[o][3];
        *(uint4*)&pool[gg * 2048 + (ty * 2 + o) * 256 + tx * 8] = v;
    }
    __syncthreads();

    {
        int base = tid * 4;
        float fs[4] = {0.f, 0.f, 0.f, 0.f};
        #pragma unroll
        for (int g = 0; g < 4; g++) {
            uint2 v = *(const uint2*)&pool[g * 2048 + base];
            float2 f0 = __half22float2(*(__half2*)&v.x);
            float2 f1 = __half22float2(*(__half2*)&v.y);
            fs[0] += f0.x; fs[1] += f0.y; fs[2] += f1.x; fs[3] += f1.y;
        }
        float bpv = bp[0];
        float4 r;
        r.x = 1.0f / (1.0f + __expf(-(fs[0] + bpv)));
        r.y = 1.0f / (1.0f + __expf(-(fs[1] + bpv)));
        r.z = 1.0f / (1.0f + __expf(-(fs[2] + bpv)));
        r.w = 1.0f / (1.0f + __expf(-(fs[3] + bpv)));
        int row = base >> 8, col = base & 255;
        *(float4*)&out[((size_t)(bb * 256) + i0 + row) * 256 + col] = r;
    }
}

// ---------------- launch ----------------

extern "C" void kernel_launch(void* const* d_in, const int* in_sizes, int n_in,
                              void* d_out, int out_size, void* d_ws, size_t ws_size,
                              hipStream_t stream) {
    const float* x  = (const float*)d_in[0];
    const int*   ei = (const int*)d_in[1];
    const float* ew = (const float*)d_in[2];
    const float* W0 = (const float*)d_in[4];
    const float* b0 = (const float*)d_in[5];
    const float* W1 = (const float*)d_in[6];
    const float* b1 = (const float*)d_in[7];
    const float* W2 = (const float*)d_in[8];
    const float* b2 = (const float*)d_in[9];
    const float* Wc = (const float*)d_in[10];
    const float* bc = (const float*)d_in[11];
    const float* Wp = (const float*)d_in[12];
    const float* bp = (const float*)d_in[13];

    char* ws = (char*)d_ws;
    float*          deg  = (float*)(ws + OFF_DEG);
    unsigned short* A16  = (unsigned short*)(ws + OFF_A);
    unsigned short* G1T  = (unsigned short*)(ws + OFF_G1T);
    unsigned short* G2T  = (unsigned short*)(ws + OFF_G2T);
    unsigned short* G3T  = (unsigned short*)(ws + OFF_G3T);
    unsigned short* H3   = (unsigned short*)(ws + OFF_H3);
    unsigned int*   w2t  = (unsigned int*)(ws + OFF_W2T);

    (void)hipMemsetAsync(deg, 0, 16384, stream);

    k_zerodeg<<<1024, 256, 0, stream>>>(ei, ew, deg, A16);
    k_scatter<<<NE/256, 256, 0, stream>>>(ei, ew, deg, A16, x, W0, G1T, Wp, w2t);

    k_gcn<16, 32, false><<<256, 512, 0, stream>>>(A16, G1T, b0, W1, G2T);
    k_gcn<32, 32, false><<<256, 512, 0, stream>>>(A16, G2T, b1, W2, G3T);
    k_gcn<32, 32, true> <<<256, 512, 0, stream>>>(A16, G3T, b2, nullptr, H3);

    k_cc<<<dim3(32, 16), 512, 0, stream>>>(H3, Wc, bc, w2t, bp, (float*)d_out);
}

// Round 11
// 192.421 us; speedup vs baseline: 1.0933x; 1.0201x over previous
//
#include <hip/hip_runtime.h>
#include <hip/hip_bf16.h>
#include <hip/hip_fp16.h>

#define NT 4096
#define NE 131072

// ws layout (bytes)
#define OFF_DEG  0            // float[4096]
#define OFF_A    16384        // bf16[4096*4096] = 32 MiB
#define OFF_G1T  33570816     // bf16[16][4096]
#define OFF_G2T  33701888     // bf16[32][4096]
#define OFF_G3T  33964032     // bf16[32][4096]
#define OFF_H3   34226176     // bf16[4096][32]
#define OFF_W2T  34488320     // uint[1568]
// total ~34.5 MB

typedef __attribute__((ext_vector_type(8))) short bf16x8;
typedef __attribute__((ext_vector_type(4))) float f32x4;

__device__ inline unsigned int align16(unsigned int hi, unsigned int lo) {
#if __has_builtin(__builtin_amdgcn_alignbit)
    return __builtin_amdgcn_alignbit(hi, lo, 16);
#else
    return (lo >> 16) | (hi << 16);
#endif
}

__device__ inline unsigned short bfb(float x) {
    return __hip_bfloat16_raw(__float2bfloat16(x)).x;
}

__device__ inline void atomic_add_bf16(unsigned short* base, unsigned int idx, float v) {
    unsigned long long addr = (unsigned long long)(base + (idx & ~1u));
    unsigned int bits = ((unsigned int)bfb(v)) << ((idx & 1u) * 16);
    asm volatile("global_atomic_pk_add_bf16 %0, %1, off" :: "v"(addr), "v"(bits) : "memory");
}

// ---------------- setup ----------------

__global__ __launch_bounds__(256) void k_zerodeg(const int* __restrict__ ei,
                                                 const float* __restrict__ ew,
                                                 float* __restrict__ deg,
                                                 unsigned short* __restrict__ A16) {
    int blk = blockIdx.x, tid = threadIdx.x;
    uint4 z4 = {0u, 0u, 0u, 0u};
    uint4* ap = (uint4*)(A16 + (size_t)blk * 16384);
    #pragma unroll
    for (int k = 0; k < 8; k++) ap[tid + k * 256] = z4;
    int gid = blk * 256 + tid;
    if (gid < NE) atomicAdd(&deg[ei[NE + gid]], ew[gid]);
}

__global__ void k_scatter(const int* __restrict__ ei, const float* __restrict__ ew,
                          const float* __restrict__ deg, unsigned short* __restrict__ A16,
                          const float* __restrict__ x, const float* __restrict__ W0,
                          unsigned short* __restrict__ G1T,
                          const float* __restrict__ Wp, unsigned int* __restrict__ w2) {
    int e = blockIdx.x * 256 + threadIdx.x;
    if (e < NE) {
        int s = ei[e], d = ei[NE + e];
        float v = rsqrtf(deg[s] + 2.f) * ew[e] * rsqrtf(deg[d] + 2.f);
        atomic_add_bf16(A16, (unsigned int)d * 4096u + (unsigned int)s, v);
    }
    if (e < NT) {
        atomic_add_bf16(A16, (unsigned int)e * 4097u, 2.f / (deg[e] + 2.f));
    }
    if (e < NT * 16) {
        int node = e & 4095, co = e >> 12;
        const float4* xr = (const float4*)(x + node * 32);
        float a = 0.f;
        #pragma unroll
        for (int r = 0; r < 8; r++) {
            float4 f = xr[r];
            a += f.x * W0[(r*4+0)*16 + co] + f.y * W0[(r*4+1)*16 + co]
               + f.z * W0[(r*4+2)*16 + co] + f.w * W0[(r*4+3)*16 + co];
        }
        G1T[co * 4096 + node] = bfb(a);
    }
    if (e >= NE - 1568) {
        int k = e - (NE - 1568);
        __half hh = __float2half(Wp[k]);
        __half2 h2 = __halves2half2(hh, hh);
        w2[k] = *(unsigned int*)&h2;
    }
}

// ---------------- GCN layer via dense-A MFMA ----------------
// 256 blocks x 1024 thr (16 waves, 4/SIMD). Wave w: K-window [w*256,(w+1)*256).

template <int NIN, int NOUT, bool LAST>
__global__ __launch_bounds__(1024) void k_gcn(const unsigned short* __restrict__ A16,
                                              const unsigned short* __restrict__ Gt,
                                              const float* __restrict__ bias,
                                              const float* __restrict__ W,
                                              unsigned short* __restrict__ Gout) {
    constexpr int T = NIN / 16;
    __shared__ float red[16][T][16][16];
    __shared__ unsigned short wtile[16 * 40];
    int mt = blockIdx.x;
    int tid = threadIdx.x;
    int w = tid >> 6, lane = tid & 63, m = lane & 15, q = lane >> 4;
    int kw = w * 256;

    const unsigned short* arow = A16 + (size_t)(mt * 16 + m) * 4096 + kw + q * 8;

    bf16x8 bA[8];
    #pragma unroll
    for (int s = 0; s < 8; s++) bA[s] = *(const bf16x8*)(arow + s * 32);

    f32x4 acc[T];
    #pragma unroll
    for (int t = 0; t < T; t++) acc[t] = (f32x4){0.f, 0.f, 0.f, 0.f};

    bf16x8 wfrag;
    if (!LAST && w < NOUT / 16) {
        #pragma unroll
        for (int j = 0; j < 8; j++) {
            int ci = q * 8 + j;
            wfrag[j] = (ci < NIN) ? (short)bfb(W[ci * NOUT + w * 16 + m]) : (short)0;
        }
    }

    const unsigned short* gbase = Gt + kw + q * 8 + (size_t)m * 4096;
    #pragma unroll
    for (int s = 0; s < 8; s++) {
        #pragma unroll
        for (int t = 0; t < T; t++) {
            bf16x8 af = *(const bf16x8*)(gbase + (size_t)t * 16 * 4096 + s * 32);
            acc[t] = __builtin_amdgcn_mfma_f32_16x16x32_bf16(af, bA[s], acc[t], 0, 0, 0);
        }
    }
    #pragma unroll
    for (int t = 0; t < T; t++)
        #pragma unroll
        for (int r = 0; r < 4; r++) red[w][t][q*4 + r][m] = acc[t][r];
    __syncthreads();

    if (tid < T * 256) {
        int dstp = tid & 15, cop = (tid >> 4) & 15, t = tid >> 8;
        float sum = 0.f;
        #pragma unroll
        for (int w8 = 0; w8 < 16; w8++) sum += red[w8][t][cop][dstp];
        int co = t * 16 + cop;
        float val = fmaxf(sum + bias[co], 0.f);
        if (LAST) Gout[(size_t)(mt * 16 + dstp) * 32 + co] = bfb(val);
        else      wtile[dstp * 40 + co] = bfb(val);
    }
    if (!LAST && NIN == 16 && tid >= 256 && tid < 512) {
        int idx = tid - 256;
        wtile[(idx & 15) * 40 + 16 + ((idx >> 4) & 15)] = 0;
    }
    __syncthreads();

    if (!LAST && w < NOUT / 16) {
        bf16x8 af = *(const bf16x8*)&wtile[m * 40 + q * 8];
        f32x4 o = (f32x4){0.f, 0.f, 0.f, 0.f};
        o = __builtin_amdgcn_mfma_f32_16x16x32_bf16(af, wfrag, o, 0, 0, 0);
        uint2 ov;
        ov.x = (unsigned int)bfb(o[0]) | ((unsigned int)bfb(o[1]) << 16);
        ov.y = (unsigned int)bfb(o[2]) | ((unsigned int)bfb(o[3]) << 16);
        *(uint2*)&Gout[(size_t)(w * 16 + m) * 4096 + mt * 16 + q * 4] = ov;
    }
}

// ---------------- fused C1 + 7x7 conv + sigmoid (v5) ----------------
// grid (band 32, b 16) = 512 blocks (2/CU), 512 thr. Band = 8 out rows.
// Diag-scale moved to the single-tile B (i-side); A (j-side, 2 tiles) is
// loop-invariant. B rebuild = 8 v_mul + 4 v_perm (trunc bf16) per channel.

__global__ __launch_bounds__(512, 4) void k_cc(const unsigned short* __restrict__ h3,
                                               const float* __restrict__ Wc,
                                               const float* __restrict__ bc,
                                               const unsigned int* __restrict__ w2,
                                               const float* __restrict__ bp,
                                               float* __restrict__ out) {
    __shared__ __align__(16) unsigned short pool[15680];   // 31360 B
    __shared__ float wcs[32 * 36];                         // 4608 B

    int band = blockIdx.x, bb = blockIdx.y;
    int i0 = band * 8;
    int tid = threadIdx.x;
    int lane = tid & 63, w = tid >> 6;
    int m = lane & 15, q = lane >> 4;

    // ---- stage Z_b into pool-as-zs (row stride 40 f16) ----
    {
        int row = tid >> 1, half = tid & 1;
        const uint4* src = (const uint4*)(h3 + (size_t)(bb * 256 + row) * 32) + half * 2;
        uint4 v0 = src[0], v1 = src[1];
        uint4* dst = (uint4*)&pool[row * 40 + half * 16];
        dst[0] = v0; dst[1] = v1;
    }
    #pragma unroll
    for (int k = tid; k < 1024; k += 512) wcs[(k >> 5) * 36 + (k & 31)] = Wc[k];
    __syncthreads();

    // ---- extract frags ----
    float btf[8];       // i-row frag, unpacked to f32 (for per-channel scale)
    bool wok;
    {
        int r = i0 - 3 + m;
        wok = ((unsigned)r < 256u) && (m < 14);
        int rc = r < 0 ? 0 : (r > 255 ? 255 : r);
        bf16x8 bt = *(const bf16x8*)&pool[rc * 40 + q * 8];
        #pragma unroll
        for (int e = 0; e < 8; e++)
            btf[e] = __uint_as_float(((unsigned int)(unsigned short)bt[e]) << 16);
    }
    bf16x8 af2[2];      // A: j-rows, loop-invariant (plain z)
    #pragma unroll
    for (int jt2 = 0; jt2 < 2; jt2++)
        af2[jt2] = *(const bf16x8*)&pool[((w * 2 + jt2) * 16 + m) * 40 + q * 8];
    __syncthreads();    // zs dead

    // ---- zero ct (7840 dw) ----
    for (int k = tid; k < 7840; k += 512) ((unsigned int*)pool)[k] = 0;
    __syncthreads();

    int gg = tid >> 7, idx = tid & 127;
    int tx = idx & 31, ty = idx >> 5;     // 8 px, 2 out rows
    __half2 acc[2][4];
    __half2 zh = __float2half2_rn(0.f);
    #pragma unroll
    for (int o = 0; o < 2; o++)
        #pragma unroll
        for (int p = 0; p < 4; p++) acc[o][p] = zh;

    for (int it = 0; it < 8; it++) {
        // ---- MFMA phase: channels it*4 .. it*4+3 ----
        #pragma unroll
        for (int g = 0; g < 4; g++) {
            int h = it * 4 + g;
            float wf[8];
            *(float4*)&wf[0] = *(const float4*)&wcs[h * 36 + q * 8];
            *(float4*)&wf[4] = *(const float4*)&wcs[h * 36 + q * 8 + 4];
            float bch = bc[h];
            // build scaled B via trunc-pack (v_perm)
            unsigned int bu[4];
            #pragma unroll
            for (int k = 0; k < 4; k++) {
                float m0 = btf[2*k]   * wf[2*k];
                float m1 = btf[2*k+1] * wf[2*k+1];
                bu[k] = __builtin_amdgcn_perm(__float_as_uint(m1), __float_as_uint(m0),
                                              0x07060302u);
            }
            bf16x8 btv;
            *(uint4*)&btv = make_uint4(bu[0], bu[1], bu[2], bu[3]);
            #pragma unroll
            for (int jt2 = 0; jt2 < 2; jt2++) {
                int pos = 4 + (w * 2 + jt2) * 16 + q * 4;
                f32x4 d = (f32x4){0.f, 0.f, 0.f, 0.f};
                d = __builtin_amdgcn_mfma_f32_16x16x32_bf16(af2[jt2], btv, d, 0, 0, 0);
                if (wok) {
                    float v0 = fmaxf(d[0] + bch, 0.f);
                    float v1 = fmaxf(d[1] + bch, 0.f);
                    float v2 = fmaxf(d[2] + bch, 0.f);
                    float v3 = fmaxf(d[3] + bch, 0.f);
                    __half2 h0 = __floats2half2_rn(v0, v1);
                    __half2 h1 = __floats2half2_rn(v2, v3);
                    uint2 o2;
                    o2.x = *(unsigned int*)&h0;
                    o2.y = *(unsigned int*)&h1;
                    *(uint2*)&pool[g * 3920 + m * 280 + pos] = o2;
                }
            }
        }
        __syncthreads();

        // ---- conv phase: group gg, channel it*4+gg ----
        {
            const unsigned short* C = pool + gg * 3920;
            const __half2* wrow = (const __half2*)w2 + (it * 4 + gg) * 49;
            #pragma unroll
            for (int dr = 0; dr < 8; dr++) {
                const uint4* p4 = (const uint4*)&C[(ty * 2 + dr) * 280 + tx * 8];
                uint4 ua = p4[0], ub = p4[1];
                unsigned int E[8] = {ua.x, ua.y, ua.z, ua.w, ub.x, ub.y, ub.z, ub.w};
                unsigned int O[7];
                #pragma unroll
                for (int k = 0; k < 7; k++) O[k] = align16(E[k + 1], E[k]);
                #pragma unroll
                for (int o = 0; o < 2; o++) {
                    if (dr - o < 0 || dr - o > 6) continue;
                    int di = dr - o;
                    #pragma unroll
                    for (int dj = 0; dj < 7; dj++) {
                        __half2 wv = wrow[di * 7 + dj];
                        #pragma unroll
                        for (int pr = 0; pr < 4; pr++) {
                            int s = 2 * pr + dj + 1;
                            unsigned int pv = (s & 1) ? O[s >> 1] : E[s >> 1];
                            acc[o][pr] = __hfma2(wv, *(__half2*)&pv, acc[o][pr]);
                        }
                    }
                }
            }
        }
        __syncthreads();
    }

    // ---- pt partials (pool reused), reduce, sigmoid, store ----
    #pragma unroll
    for (int o = 0; o < 2; o++) {
        uint4 v;
        v.x = *(unsigned int*)&acc[o][0];
        v.y = *(unsigned int*)&acc[o][1];
        v.z = *(unsigned int*)&acc[o][2];
        v.w = *(unsigned int*)&acc[o][3];
        *(uint4*)&pool[gg * 2048 + (ty * 2 + o) * 256 + tx * 8] = v;
    }
    __syncthreads();

    {
        int base = tid * 4;
        float fs[4] = {0.f, 0.f, 0.f, 0.f};
        #pragma unroll
        for (int g = 0; g < 4; g++) {
            uint2 v = *(const uint2*)&pool[g * 2048 + base];
            float2 f0 = __half22float2(*(__half2*)&v.x);
            float2 f1 = __half22float2(*(__half2*)&v.y);
            fs[0] += f0.x; fs[1] += f0.y; fs[2] += f1.x; fs[3] += f1.y;
        }
        float bpv = bp[0];
        float4 r;
        r.x = 1.0f / (1.0f + __expf(-(fs[0] + bpv)));
        r.y = 1.0f / (1.0f + __expf(-(fs[1] + bpv)));
        r.z = 1.0f / (1.0f + __expf(-(fs[2] + bpv)));
        r.w = 1.0f / (1.0f + __expf(-(fs[3] + bpv)));
        int row = base >> 8, col = base & 255;
        *(float4*)&out[((size_t)(bb * 256) + i0 + row) * 256 + col] = r;
    }
}

// ---------------- launch ----------------

extern "C" void kernel_launch(void* const* d_in, const int* in_sizes, int n_in,
                              void* d_out, int out_size, void* d_ws, size_t ws_size,
                              hipStream_t stream) {
    const float* x  = (const float*)d_in[0];
    const int*   ei = (const int*)d_in[1];
    const float* ew = (const float*)d_in[2];
    const float* W0 = (const float*)d_in[4];
    const float* b0 = (const float*)d_in[5];
    const float* W1 = (const float*)d_in[6];
    const float* b1 = (const float*)d_in[7];
    const float* W2 = (const float*)d_in[8];
    const float* b2 = (const float*)d_in[9];
    const float* Wc = (const float*)d_in[10];
    const float* bc = (const float*)d_in[11];
    const float* Wp = (const float*)d_in[12];
    const float* bp = (const float*)d_in[13];

    char* ws = (char*)d_ws;
    float*          deg  = (float*)(ws + OFF_DEG);
    unsigned short* A16  = (unsigned short*)(ws + OFF_A);
    unsigned short* G1T  = (unsigned short*)(ws + OFF_G1T);
    unsigned short* G2T  = (unsigned short*)(ws + OFF_G2T);
    unsigned short* G3T  = (unsigned short*)(ws + OFF_G3T);
    unsigned short* H3   = (unsigned short*)(ws + OFF_H3);
    unsigned int*   w2t  = (unsigned int*)(ws + OFF_W2T);

    (void)hipMemsetAsync(deg, 0, 16384, stream);

    k_zerodeg<<<1024, 256, 0, stream>>>(ei, ew, deg, A16);
    k_scatter<<<NE/256, 256, 0, stream>>>(ei, ew, deg, A16, x, W0, G1T, Wp, w2t);

    k_gcn<16, 32, false><<<256, 1024, 0, stream>>>(A16, G1T, b0, W1, G2T);
    k_gcn<32, 32, false><<<256, 1024, 0, stream>>>(A16, G2T, b1, W2, G3T);
    k_gcn<32, 32, true> <<<256, 1024, 0, stream>>>(A16, G3T, b2, nullptr, H3);

    k_cc<<<dim3(32, 16), 512, 0, stream>>>(H3, Wc, bc, w2t, bp, (float*)d_out);
}